// Round 1
// baseline (5040.924 us; speedup 1.0000x reference)
//
#include <hip/hip_runtime.h>

#define NN 100000
#define NE 3200000
#define NIN 16
#define ECH 16
#define F 10
#define FP 12          // padded row stride (48 B, float4-aligned)
#define OC 32

// ---------------- edge kernel: e = relu(edge_attr @ W4 + b4); agg_e[dst] += e
__global__ __launch_bounds__(256) void k_edge_e(
    const float* __restrict__ ea, const int* __restrict__ dst,
    const float* __restrict__ W4, const float* __restrict__ b4,
    float* __restrict__ agg)
{
    __shared__ float w[ECH*F + F];
    int t = threadIdx.x;
    if (t < ECH*F) w[t] = W4[t];
    if (t < F) w[ECH*F + t] = b4[t];
    __syncthreads();
    int e = blockIdx.x * 256 + t;
    if (e >= NE) return;
    const float4* p = (const float4*)(ea + (size_t)e * ECH);
    float4 v0 = p[0], v1 = p[1], v2 = p[2], v3 = p[3];
    float a[ECH] = {v0.x,v0.y,v0.z,v0.w, v1.x,v1.y,v1.z,v1.w,
                    v2.x,v2.y,v2.z,v2.w, v3.x,v3.y,v3.z,v3.w};
    float acc[F];
#pragma unroll
    for (int j = 0; j < F; ++j) acc[j] = w[ECH*F + j];
#pragma unroll
    for (int i = 0; i < ECH; ++i) {
        float ai = a[i];
#pragma unroll
        for (int j = 0; j < F; ++j) acc[j] = fmaf(ai, w[i*F + j], acc[j]);
    }
    int d = dst[e];
    float* row = agg + (size_t)d * FP;
#pragma unroll
    for (int j = 0; j < F; ++j) {
        float r = acc[j] > 0.f ? acc[j] : 0.f;
        atomicAdd(row + j, r);
    }
}

// ---------------- node init: base = x@W1 + agg_e@W3 + (b1+b2+b3); feat = relu(base)
__global__ __launch_bounds__(256) void k_node_init(
    const float* __restrict__ x, const float* __restrict__ agg_e,
    const float* __restrict__ W1, const float* __restrict__ b1,
    const float* __restrict__ W3, const float* __restrict__ b3,
    const float* __restrict__ b2,
    float* __restrict__ base, float* __restrict__ feat)
{
    __shared__ float w1[NIN*F], w3[F*F], bb[F];
    int t = threadIdx.x;
    if (t < NIN*F) w1[t] = W1[t];
    if (t < F*F) w3[t] = W3[t];
    if (t < F) bb[t] = b1[t] + b2[t] + b3[t];
    __syncthreads();
    int n = blockIdx.x * 256 + t;
    if (n >= NN) return;
    const float4* px = (const float4*)(x + (size_t)n * NIN);
    float4 x0 = px[0], x1 = px[1], x2 = px[2], x3 = px[3];
    float xv[NIN] = {x0.x,x0.y,x0.z,x0.w, x1.x,x1.y,x1.z,x1.w,
                     x2.x,x2.y,x2.z,x2.w, x3.x,x3.y,x3.z,x3.w};
    const float4* pa = (const float4*)(agg_e + (size_t)n * FP);
    float4 a0 = pa[0], a1 = pa[1], a2 = pa[2];
    float av[F] = {a0.x,a0.y,a0.z,a0.w, a1.x,a1.y,a1.z,a1.w, a2.x,a2.y};
    float acc[F];
#pragma unroll
    for (int j = 0; j < F; ++j) acc[j] = bb[j];
#pragma unroll
    for (int i = 0; i < NIN; ++i) {
        float xi = xv[i];
#pragma unroll
        for (int j = 0; j < F; ++j) acc[j] = fmaf(xi, w1[i*F + j], acc[j]);
    }
#pragma unroll
    for (int i = 0; i < F; ++i) {
        float ai = av[i];
#pragma unroll
        for (int j = 0; j < F; ++j) acc[j] = fmaf(ai, w3[i*F + j], acc[j]);
    }
    float4* pb = (float4*)(base + (size_t)n * FP);
    pb[0] = make_float4(acc[0], acc[1], acc[2], acc[3]);
    pb[1] = make_float4(acc[4], acc[5], acc[6], acc[7]);
    pb[2] = make_float4(acc[8], acc[9], 0.f, 0.f);
    float r[F];
#pragma unroll
    for (int j = 0; j < F; ++j) r[j] = acc[j] > 0.f ? acc[j] : 0.f;
    float4* pf = (float4*)(feat + (size_t)n * FP);
    pf[0] = make_float4(r[0], r[1], r[2], r[3]);
    pf[1] = make_float4(r[4], r[5], r[6], r[7]);
    pf[2] = make_float4(r[8], r[9], 0.f, 0.f);
}

// ---------------- edge scatter: aggb[dst] += feat[src]   (aggb pre-initialized to feat)
__global__ __launch_bounds__(256) void k_edge_scatter(
    const int* __restrict__ src, const int* __restrict__ dst,
    const float* __restrict__ feat, float* __restrict__ aggb)
{
    int e = blockIdx.x * 256 + threadIdx.x;
    if (e >= NE) return;
    int s = src[e], d = dst[e];
    const float4* p = (const float4*)(feat + (size_t)s * FP);
    float4 v0 = p[0], v1 = p[1], v2 = p[2];
    float v[F] = {v0.x,v0.y,v0.z,v0.w, v1.x,v1.y,v1.z,v1.w, v2.x,v2.y};
    float* row = aggb + (size_t)d * FP;
#pragma unroll
    for (int j = 0; j < F; ++j) atomicAdd(row + j, v[j]);
}

// ---------------- node update: feat = relu(base + aggb @ W2)
__global__ __launch_bounds__(256) void k_node_update(
    const float* __restrict__ base, const float* __restrict__ aggb,
    const float* __restrict__ W2, float* __restrict__ feat)
{
    __shared__ float w2[F*F];
    int t = threadIdx.x;
    if (t < F*F) w2[t] = W2[t];
    __syncthreads();
    int n = blockIdx.x * 256 + t;
    if (n >= NN) return;
    const float4* pb = (const float4*)(base + (size_t)n * FP);
    float4 b0 = pb[0], b1v = pb[1], b2v = pb[2];
    float acc[F] = {b0.x,b0.y,b0.z,b0.w, b1v.x,b1v.y,b1v.z,b1v.w, b2v.x,b2v.y};
    const float4* pa = (const float4*)(aggb + (size_t)n * FP);
    float4 a0 = pa[0], a1 = pa[1], a2 = pa[2];
    float av[F] = {a0.x,a0.y,a0.z,a0.w, a1.x,a1.y,a1.z,a1.w, a2.x,a2.y};
#pragma unroll
    for (int i = 0; i < F; ++i) {
        float ai = av[i];
#pragma unroll
        for (int j = 0; j < F; ++j) acc[j] = fmaf(ai, w2[i*F + j], acc[j]);
    }
    float r[F];
#pragma unroll
    for (int j = 0; j < F; ++j) r[j] = acc[j] > 0.f ? acc[j] : 0.f;
    float4* pf = (float4*)(feat + (size_t)n * FP);
    pf[0] = make_float4(r[0], r[1], r[2], r[3]);
    pf[1] = make_float4(r[4], r[5], r[6], r[7]);
    pf[2] = make_float4(r[8], r[9], 0.f, 0.f);
}

// ---------------- column sum of feat -> gcol[10]
__global__ __launch_bounds__(256) void k_colsum(
    const float* __restrict__ feat, float* __restrict__ gcol)
{
    int n = blockIdx.x * 256 + threadIdx.x;
    float v[F];
#pragma unroll
    for (int j = 0; j < F; ++j) v[j] = 0.f;
    if (n < NN) {
        const float4* p = (const float4*)(feat + (size_t)n * FP);
        float4 v0 = p[0], v1 = p[1], v2 = p[2];
        v[0]=v0.x; v[1]=v0.y; v[2]=v0.z; v[3]=v0.w;
        v[4]=v1.x; v[5]=v1.y; v[6]=v1.z; v[7]=v1.w;
        v[8]=v2.x; v[9]=v2.y;
    }
#pragma unroll
    for (int off = 32; off > 0; off >>= 1) {
#pragma unroll
        for (int j = 0; j < F; ++j) v[j] += __shfl_down(v[j], off);
    }
    if ((threadIdx.x & 63) == 0) {
#pragma unroll
        for (int j = 0; j < F; ++j) atomicAdd(&gcol[j], v[j]);
    }
}

// ---------------- tiny: g = gcol@W6+b6; gpart = relu(g)@W5[0:10] + b5
__global__ void k_gsmall(
    const float* __restrict__ gcol, const float* __restrict__ W6,
    const float* __restrict__ b6, const float* __restrict__ W5,
    const float* __restrict__ b5, float* __restrict__ gpart)
{
    __shared__ float r1[F];
    int t = threadIdx.x;
    if (t < F) {
        float acc = b6[t];
        for (int i = 0; i < F; ++i) acc = fmaf(gcol[i], W6[i*F + t], acc);
        r1[t] = acc > 0.f ? acc : 0.f;
    }
    __syncthreads();
    if (t < OC) {
        float acc = b5[t];
        for (int i = 0; i < F; ++i) acc = fmaf(r1[i], W5[i*OC + t], acc);
        gpart[t] = acc;
    }
}

// ---------------- output: out = gpart + relu(feat@W7+b7) @ W5[10:20]
__global__ __launch_bounds__(256) void k_out(
    const float* __restrict__ feat, const float* __restrict__ W7,
    const float* __restrict__ b7, const float* __restrict__ W5,
    const float* __restrict__ gpart, float* __restrict__ out)
{
    __shared__ float w7[F*F], bb7[F], w5[F*OC], gp[OC];
    int t = threadIdx.x;
    if (t < F*F) w7[t] = W7[t];
    if (t < F) bb7[t] = b7[t];
    if (t < F*OC) w5[t] = W5[F*OC + t];   // rows 10..19
    if (t < OC) gp[t] = gpart[t];
    __syncthreads();
    int n = blockIdx.x * 256 + t;
    if (n >= NN) return;
    const float4* p = (const float4*)(feat + (size_t)n * FP);
    float4 v0 = p[0], v1 = p[1], v2 = p[2];
    float f[F] = {v0.x,v0.y,v0.z,v0.w, v1.x,v1.y,v1.z,v1.w, v2.x,v2.y};
    float h[F];
#pragma unroll
    for (int j = 0; j < F; ++j) h[j] = bb7[j];
#pragma unroll
    for (int i = 0; i < F; ++i) {
        float fi = f[i];
#pragma unroll
        for (int j = 0; j < F; ++j) h[j] = fmaf(fi, w7[i*F + j], h[j]);
    }
#pragma unroll
    for (int j = 0; j < F; ++j) h[j] = h[j] > 0.f ? h[j] : 0.f;
    float o[OC];
#pragma unroll
    for (int k = 0; k < OC; ++k) o[k] = gp[k];
#pragma unroll
    for (int j = 0; j < F; ++j) {
        float hj = h[j];
#pragma unroll
        for (int k = 0; k < OC; ++k) o[k] = fmaf(hj, w5[j*OC + k], o[k]);
    }
    float4* po = (float4*)(out + (size_t)n * OC);
#pragma unroll
    for (int k = 0; k < 8; ++k)
        po[k] = make_float4(o[4*k], o[4*k+1], o[4*k+2], o[4*k+3]);
}

extern "C" void kernel_launch(void* const* d_in, const int* in_sizes, int n_in,
                              void* d_out, int out_size, void* d_ws, size_t ws_size,
                              hipStream_t stream)
{
    const float* x   = (const float*)d_in[0];
    const int*   ei  = (const int*)d_in[1];
    const float* ea  = (const float*)d_in[2];
    const float* W1  = (const float*)d_in[3];
    const float* b1  = (const float*)d_in[4];
    const float* W2  = (const float*)d_in[5];
    const float* b2  = (const float*)d_in[6];
    const float* W3  = (const float*)d_in[7];
    const float* b3  = (const float*)d_in[8];
    const float* W4  = (const float*)d_in[9];
    const float* b4  = (const float*)d_in[10];
    const float* W5  = (const float*)d_in[11];
    const float* b5  = (const float*)d_in[12];
    const float* W6  = (const float*)d_in[13];
    const float* b6  = (const float*)d_in[14];
    const float* W7  = (const float*)d_in[15];
    const float* b7  = (const float*)d_in[16];

    const int* src = ei;            // edge_index[0]
    const int* dst = ei + NE;       // edge_index[1]

    float* ws    = (float*)d_ws;
    float* agg_e = ws;                         // NN*FP
    float* base  = agg_e + (size_t)NN * FP;    // NN*FP
    float* feat  = base  + (size_t)NN * FP;    // NN*FP
    float* aggb  = feat  + (size_t)NN * FP;    // NN*FP
    float* gcol  = aggb  + (size_t)NN * FP;    // 16
    float* gpart = gcol + 16;                  // 32

    const int EB = (NE + 255) / 256;
    const int NB = (NN + 255) / 256;

    hipMemsetAsync(agg_e, 0, (size_t)NN * FP * sizeof(float), stream);
    hipMemsetAsync(gcol, 0, 16 * sizeof(float), stream);

    k_edge_e<<<EB, 256, 0, stream>>>(ea, dst, W4, b4, agg_e);
    k_node_init<<<NB, 256, 0, stream>>>(x, agg_e, W1, b1, W3, b3, b2, base, feat);

    // reference ITERS=3, but iteration 1 starts from features==0 -> feat = relu(base).
    // Only 2 propagation iterations remain.
    for (int it = 0; it < 2; ++it) {
        hipMemcpyAsync(aggb, feat, (size_t)NN * FP * sizeof(float),
                       hipMemcpyDeviceToDevice, stream);
        k_edge_scatter<<<EB, 256, 0, stream>>>(src, dst, feat, aggb);
        k_node_update<<<NB, 256, 0, stream>>>(base, aggb, W2, feat);
    }

    k_colsum<<<NB, 256, 0, stream>>>(feat, gcol);
    k_gsmall<<<1, 64, 0, stream>>>(gcol, W6, b6, W5, b5, gpart);
    k_out<<<NB, 256, 0, stream>>>(feat, W7, b7, W5, gpart, (float*)d_out);
}

// Round 2
// 935.361 us; speedup vs baseline: 5.3893x; 5.3893x over previous
//
#include <hip/hip_runtime.h>

#define NN 100000
#define NE 3200000
#define NIN 16
#define ECH 16
#define F 10
#define FP 12          // padded node row stride (48 B, float4-aligned)
#define OC 32

// ---------- pass 1: histogram of dst
__global__ __launch_bounds__(256) void k_hist(const int* __restrict__ dst,
                                              int* __restrict__ cnt)
{
    int e = blockIdx.x * 256 + threadIdx.x;
    if (e < NE) atomicAdd(&cnt[dst[e]], 1);
}

// ---------- pass 2: exclusive scan of cnt -> offs (single block, 1024 threads)
__global__ __launch_bounds__(1024) void k_scan(const int* __restrict__ cnt,
                                               int* __restrict__ offs)
{
    __shared__ int wsum[16], wscan[16];
    int t = threadIdx.x;
    const int CH = (NN + 1023) / 1024;   // 98
    int begin = t * CH;
    int end = begin + CH; if (end > NN) end = NN;
    if (begin > NN) begin = NN;
    int s = 0;
    for (int i = begin; i < end; ++i) s += cnt[i];
    int lane = t & 63, w = t >> 6;
    int v = s;
    for (int d = 1; d < 64; d <<= 1) { int u = __shfl_up(v, d); if (lane >= d) v += u; }
    if (lane == 63) wsum[w] = v;
    __syncthreads();
    if (t < 16) {
        int u = wsum[t];
        for (int d = 1; d < 16; d <<= 1) { int x2 = __shfl_up(u, d); if (t >= d) u += x2; }
        wscan[t] = u;
    }
    __syncthreads();
    int ex = (w > 0 ? wscan[w - 1] : 0) + (v - s);   // exclusive prefix for this thread
    int run = ex;
    for (int i = begin; i < end; ++i) { offs[i] = run; run += cnt[i]; }
    if (t == 1023) offs[NN] = NE;
}

// ---------- pass 3: place edges into CSR slots
__global__ __launch_bounds__(256) void k_place(
    const int* __restrict__ src, const int* __restrict__ dst,
    const int* __restrict__ offs, int* __restrict__ cursor,
    int* __restrict__ src_sorted, int* __restrict__ eid_sorted)
{
    int e = blockIdx.x * 256 + threadIdx.x;
    if (e >= NE) return;
    int d = dst[e];
    int p = offs[d] + atomicAdd(&cursor[d], 1);
    src_sorted[p] = src[e];
    eid_sorted[p] = e;
}

// ---------- fused: agg_e (gather over in-edges of relu(ea@W4+b4)) + node init
__global__ __launch_bounds__(256) void k_init(
    const float* __restrict__ x, const float* __restrict__ ea,
    const int* __restrict__ eids, const int* __restrict__ offs,
    const float* __restrict__ W1, const float* __restrict__ b1,
    const float* __restrict__ b2,
    const float* __restrict__ W3, const float* __restrict__ b3,
    const float* __restrict__ W4, const float* __restrict__ b4,
    float* __restrict__ base, float* __restrict__ feat)
{
    __shared__ float w1[NIN*F], w3[F*F], w4[ECH*F], bb[F], b4s[F];
    int t = threadIdx.x;
    if (t < NIN*F) w1[t] = W1[t];
    if (t < F*F)   w3[t] = W3[t];
    if (t < ECH*F) w4[t] = W4[t];
    if (t < F) { bb[t] = b1[t] + b2[t] + b3[t]; b4s[t] = b4[t]; }
    __syncthreads();
    int n = blockIdx.x * 256 + t;
    if (n >= NN) return;
    int p0 = offs[n], p1 = offs[n + 1];
    float agg[F];
#pragma unroll
    for (int j = 0; j < F; ++j) agg[j] = 0.f;
    int p = p0;
    for (; p + 1 < p1; p += 2) {               // 2-deep to overlap HBM latency
        int e0 = eids[p], e1 = eids[p + 1];
        const float4* q0 = (const float4*)(ea + (size_t)e0 * ECH);
        const float4* q1 = (const float4*)(ea + (size_t)e1 * ECH);
        float4 a0 = q0[0], a1 = q0[1], a2 = q0[2], a3 = q0[3];
        float4 c0 = q1[0], c1 = q1[1], c2 = q1[2], c3 = q1[3];
        float av[ECH] = {a0.x,a0.y,a0.z,a0.w, a1.x,a1.y,a1.z,a1.w,
                         a2.x,a2.y,a2.z,a2.w, a3.x,a3.y,a3.z,a3.w};
        float cv[ECH] = {c0.x,c0.y,c0.z,c0.w, c1.x,c1.y,c1.z,c1.w,
                         c2.x,c2.y,c2.z,c2.w, c3.x,c3.y,c3.z,c3.w};
        float ev[F], fv[F];
#pragma unroll
        for (int j = 0; j < F; ++j) { ev[j] = b4s[j]; fv[j] = b4s[j]; }
#pragma unroll
        for (int i = 0; i < ECH; ++i) {
            float ai = av[i], ci = cv[i];
#pragma unroll
            for (int j = 0; j < F; ++j) {
                ev[j] = fmaf(ai, w4[i*F + j], ev[j]);
                fv[j] = fmaf(ci, w4[i*F + j], fv[j]);
            }
        }
#pragma unroll
        for (int j = 0; j < F; ++j) agg[j] += fmaxf(ev[j], 0.f) + fmaxf(fv[j], 0.f);
    }
    if (p < p1) {
        int e0 = eids[p];
        const float4* q0 = (const float4*)(ea + (size_t)e0 * ECH);
        float4 a0 = q0[0], a1 = q0[1], a2 = q0[2], a3 = q0[3];
        float av[ECH] = {a0.x,a0.y,a0.z,a0.w, a1.x,a1.y,a1.z,a1.w,
                         a2.x,a2.y,a2.z,a2.w, a3.x,a3.y,a3.z,a3.w};
        float ev[F];
#pragma unroll
        for (int j = 0; j < F; ++j) ev[j] = b4s[j];
#pragma unroll
        for (int i = 0; i < ECH; ++i) {
            float ai = av[i];
#pragma unroll
            for (int j = 0; j < F; ++j) ev[j] = fmaf(ai, w4[i*F + j], ev[j]);
        }
#pragma unroll
        for (int j = 0; j < F; ++j) agg[j] += fmaxf(ev[j], 0.f);
    }
    const float4* px = (const float4*)(x + (size_t)n * NIN);
    float4 x0 = px[0], x1 = px[1], x2 = px[2], x3 = px[3];
    float xv[NIN] = {x0.x,x0.y,x0.z,x0.w, x1.x,x1.y,x1.z,x1.w,
                     x2.x,x2.y,x2.z,x2.w, x3.x,x3.y,x3.z,x3.w};
    float acc[F];
#pragma unroll
    for (int j = 0; j < F; ++j) acc[j] = bb[j];
#pragma unroll
    for (int i = 0; i < NIN; ++i) {
        float xi = xv[i];
#pragma unroll
        for (int j = 0; j < F; ++j) acc[j] = fmaf(xi, w1[i*F + j], acc[j]);
    }
#pragma unroll
    for (int i = 0; i < F; ++i) {
        float ai = agg[i];
#pragma unroll
        for (int j = 0; j < F; ++j) acc[j] = fmaf(ai, w3[i*F + j], acc[j]);
    }
    float4* pb = (float4*)(base + (size_t)n * FP);
    pb[0] = make_float4(acc[0], acc[1], acc[2], acc[3]);
    pb[1] = make_float4(acc[4], acc[5], acc[6], acc[7]);
    pb[2] = make_float4(acc[8], acc[9], 0.f, 0.f);
    float4* pf = (float4*)(feat + (size_t)n * FP);
    pf[0] = make_float4(fmaxf(acc[0],0.f), fmaxf(acc[1],0.f), fmaxf(acc[2],0.f), fmaxf(acc[3],0.f));
    pf[1] = make_float4(fmaxf(acc[4],0.f), fmaxf(acc[5],0.f), fmaxf(acc[6],0.f), fmaxf(acc[7],0.f));
    pf[2] = make_float4(fmaxf(acc[8],0.f), fmaxf(acc[9],0.f), 0.f, 0.f);
}

// ---------- one propagation iteration: featN = relu(base + (gather-sum + self) @ W2)
__global__ __launch_bounds__(256) void k_iter(
    const int* __restrict__ srcs, const int* __restrict__ offs,
    const float* __restrict__ featO, const float* __restrict__ base,
    const float* __restrict__ W2, float* __restrict__ featN)
{
    __shared__ float w2[F*F];
    int t = threadIdx.x;
    if (t < F*F) w2[t] = W2[t];
    __syncthreads();
    int n = blockIdx.x * 256 + t;
    if (n >= NN) return;
    int p0 = offs[n], p1 = offs[n + 1];
    const float4* ps = (const float4*)(featO + (size_t)n * FP);
    float4 s0 = ps[0], s1 = ps[1], s2 = ps[2];
    float agg[F] = {s0.x,s0.y,s0.z,s0.w, s1.x,s1.y,s1.z,s1.w, s2.x,s2.y};
    int p = p0;
    for (; p + 1 < p1; p += 2) {
        int a = srcs[p], b = srcs[p + 1];
        const float4* qa = (const float4*)(featO + (size_t)a * FP);
        const float4* qb = (const float4*)(featO + (size_t)b * FP);
        float4 a0 = qa[0], a1 = qa[1], a2 = qa[2];
        float4 b0 = qb[0], b1 = qb[1], b2 = qb[2];
        agg[0] += a0.x + b0.x;  agg[1] += a0.y + b0.y;
        agg[2] += a0.z + b0.z;  agg[3] += a0.w + b0.w;
        agg[4] += a1.x + b1.x;  agg[5] += a1.y + b1.y;
        agg[6] += a1.z + b1.z;  agg[7] += a1.w + b1.w;
        agg[8] += a2.x + b2.x;  agg[9] += a2.y + b2.y;
    }
    if (p < p1) {
        int a = srcs[p];
        const float4* qa = (const float4*)(featO + (size_t)a * FP);
        float4 a0 = qa[0], a1 = qa[1], a2 = qa[2];
        agg[0] += a0.x; agg[1] += a0.y; agg[2] += a0.z; agg[3] += a0.w;
        agg[4] += a1.x; agg[5] += a1.y; agg[6] += a1.z; agg[7] += a1.w;
        agg[8] += a2.x; agg[9] += a2.y;
    }
    const float4* pb = (const float4*)(base + (size_t)n * FP);
    float4 c0 = pb[0], c1 = pb[1], c2 = pb[2];
    float acc[F] = {c0.x,c0.y,c0.z,c0.w, c1.x,c1.y,c1.z,c1.w, c2.x,c2.y};
#pragma unroll
    for (int i = 0; i < F; ++i) {
        float ai = agg[i];
#pragma unroll
        for (int j = 0; j < F; ++j) acc[j] = fmaf(ai, w2[i*F + j], acc[j]);
    }
    float4* pf = (float4*)(featN + (size_t)n * FP);
    pf[0] = make_float4(fmaxf(acc[0],0.f), fmaxf(acc[1],0.f), fmaxf(acc[2],0.f), fmaxf(acc[3],0.f));
    pf[1] = make_float4(fmaxf(acc[4],0.f), fmaxf(acc[5],0.f), fmaxf(acc[6],0.f), fmaxf(acc[7],0.f));
    pf[2] = make_float4(fmaxf(acc[8],0.f), fmaxf(acc[9],0.f), 0.f, 0.f);
}

// ---------- column sum of feat -> gcol[10]
__global__ __launch_bounds__(256) void k_colsum(
    const float* __restrict__ feat, float* __restrict__ gcol)
{
    int n = blockIdx.x * 256 + threadIdx.x;
    float v[F];
#pragma unroll
    for (int j = 0; j < F; ++j) v[j] = 0.f;
    if (n < NN) {
        const float4* p = (const float4*)(feat + (size_t)n * FP);
        float4 v0 = p[0], v1 = p[1], v2 = p[2];
        v[0]=v0.x; v[1]=v0.y; v[2]=v0.z; v[3]=v0.w;
        v[4]=v1.x; v[5]=v1.y; v[6]=v1.z; v[7]=v1.w;
        v[8]=v2.x; v[9]=v2.y;
    }
#pragma unroll
    for (int off = 32; off > 0; off >>= 1) {
#pragma unroll
        for (int j = 0; j < F; ++j) v[j] += __shfl_down(v[j], off);
    }
    if ((threadIdx.x & 63) == 0) {
#pragma unroll
        for (int j = 0; j < F; ++j) atomicAdd(&gcol[j], v[j]);
    }
}

// ---------- tiny: g = gcol@W6+b6; gpart = relu(g)@W5[0:10] + b5
__global__ void k_gsmall(
    const float* __restrict__ gcol, const float* __restrict__ W6,
    const float* __restrict__ b6, const float* __restrict__ W5,
    const float* __restrict__ b5, float* __restrict__ gpart)
{
    __shared__ float r1[F];
    int t = threadIdx.x;
    if (t < F) {
        float acc = b6[t];
        for (int i = 0; i < F; ++i) acc = fmaf(gcol[i], W6[i*F + t], acc);
        r1[t] = acc > 0.f ? acc : 0.f;
    }
    __syncthreads();
    if (t < OC) {
        float acc = b5[t];
        for (int i = 0; i < F; ++i) acc = fmaf(r1[i], W5[i*OC + t], acc);
        gpart[t] = acc;
    }
}

// ---------- output: out = gpart + relu(feat@W7+b7) @ W5[10:20]
__global__ __launch_bounds__(256) void k_out(
    const float* __restrict__ feat, const float* __restrict__ W7,
    const float* __restrict__ b7, const float* __restrict__ W5,
    const float* __restrict__ gpart, float* __restrict__ out)
{
    __shared__ float w7[F*F], bb7[F], w5[F*OC], gp[OC];
    int t = threadIdx.x;
    if (t < F*F) w7[t] = W7[t];
    if (t < F) bb7[t] = b7[t];
    for (int i = t; i < F*OC; i += 256) w5[i] = W5[F*OC + i];   // rows 10..19 (fixed loader)
    if (t < OC) gp[t] = gpart[t];
    __syncthreads();
    int n = blockIdx.x * 256 + t;
    if (n >= NN) return;
    const float4* p = (const float4*)(feat + (size_t)n * FP);
    float4 v0 = p[0], v1 = p[1], v2 = p[2];
    float f[F] = {v0.x,v0.y,v0.z,v0.w, v1.x,v1.y,v1.z,v1.w, v2.x,v2.y};
    float h[F];
#pragma unroll
    for (int j = 0; j < F; ++j) h[j] = bb7[j];
#pragma unroll
    for (int i = 0; i < F; ++i) {
        float fi = f[i];
#pragma unroll
        for (int j = 0; j < F; ++j) h[j] = fmaf(fi, w7[i*F + j], h[j]);
    }
#pragma unroll
    for (int j = 0; j < F; ++j) h[j] = h[j] > 0.f ? h[j] : 0.f;
    float o[OC];
#pragma unroll
    for (int k = 0; k < OC; ++k) o[k] = gp[k];
#pragma unroll
    for (int j = 0; j < F; ++j) {
        float hj = h[j];
#pragma unroll
        for (int k = 0; k < OC; ++k) o[k] = fmaf(hj, w5[j*OC + k], o[k]);
    }
    float4* po = (float4*)(out + (size_t)n * OC);
#pragma unroll
    for (int k = 0; k < 8; ++k)
        po[k] = make_float4(o[4*k], o[4*k+1], o[4*k+2], o[4*k+3]);
}

extern "C" void kernel_launch(void* const* d_in, const int* in_sizes, int n_in,
                              void* d_out, int out_size, void* d_ws, size_t ws_size,
                              hipStream_t stream)
{
    const float* x   = (const float*)d_in[0];
    const int*   ei  = (const int*)d_in[1];
    const float* ea  = (const float*)d_in[2];
    const float* W1  = (const float*)d_in[3];
    const float* b1  = (const float*)d_in[4];
    const float* W2  = (const float*)d_in[5];
    const float* b2  = (const float*)d_in[6];
    const float* W3  = (const float*)d_in[7];
    const float* b3  = (const float*)d_in[8];
    const float* W4  = (const float*)d_in[9];
    const float* b4  = (const float*)d_in[10];
    const float* W5  = (const float*)d_in[11];
    const float* b5  = (const float*)d_in[12];
    const float* W6  = (const float*)d_in[13];
    const float* b6  = (const float*)d_in[14];
    const float* W7  = (const float*)d_in[15];
    const float* b7  = (const float*)d_in[16];

    const int* src = ei;            // edge_index[0]
    const int* dst = ei + NE;       // edge_index[1]

    // workspace layout (all 16B-aligned chunks)
    char* w = (char*)d_ws;
    int* cnt        = (int*)w;                 w += (size_t)NN * 4;        // zeroed
    int* cursor     = (int*)w;                 w += (size_t)NN * 4;        // zeroed (contiguous with cnt)
    int* offs       = (int*)w;                 w += (size_t)(NN + 16) * 4;
    int* src_sorted = (int*)w;                 w += (size_t)NE * 4;
    int* eid_sorted = (int*)w;                 w += (size_t)NE * 4;
    float* base     = (float*)w;               w += (size_t)NN * FP * 4;
    float* featA    = (float*)w;               w += (size_t)NN * FP * 4;
    float* featB    = (float*)w;               w += (size_t)NN * FP * 4;
    float* gcol     = (float*)w;               w += 16 * 4;
    float* gpart    = (float*)w;               w += 32 * 4;

    const int EB = (NE + 255) / 256;
    const int NB = (NN + 255) / 256;

    hipMemsetAsync(cnt, 0, (size_t)2 * NN * 4, stream);   // cnt + cursor
    hipMemsetAsync(gcol, 0, 16 * 4, stream);

    k_hist <<<EB, 256, 0, stream>>>(dst, cnt);
    k_scan <<<1, 1024, 0, stream>>>(cnt, offs);
    k_place<<<EB, 256, 0, stream>>>(src, dst, offs, cursor, src_sorted, eid_sorted);

    k_init <<<NB, 256, 0, stream>>>(x, ea, eid_sorted, offs,
                                    W1, b1, b2, W3, b3, W4, b4, base, featA);

    k_iter <<<NB, 256, 0, stream>>>(src_sorted, offs, featA, base, W2, featB);
    k_iter <<<NB, 256, 0, stream>>>(src_sorted, offs, featB, base, W2, featA);

    k_colsum<<<NB, 256, 0, stream>>>(featA, gcol);
    k_gsmall<<<1, 64, 0, stream>>>(gcol, W6, b6, W5, b5, gpart);
    k_out  <<<NB, 256, 0, stream>>>(featA, W7, b7, W5, gpart, (float*)d_out);
}